// Round 19
// baseline (51.459 us; speedup 1.0000x reference)
//
#include <hip/hip_runtime.h>
#include <hip/hip_fp16.h>
#include <float.h>

#define N_ROWS   131072
#define DIM      64
#define NCODES   1024
#define MB       128     // rows per block
#define TPB      512     // 8 waves
#define NCHUNK   16      // 64 codes per chunk
#define NBLK     (N_ROWS / MB)   // 1024

typedef __attribute__((ext_vector_type(8))) short short8;
typedef __attribute__((ext_vector_type(4))) float floatx4;

// ws layout (bytes):
// [0,     4096)   nh      f32[1024]    64 - 512*||e_k||^2
// [4096,  36864)  counts8 i32[8][1024] sharded histogram (blockIdx&7)
// [36864, 40960)  ssePart f32[1024]
// [40960, 172032) blob: per (chunk c, quarter q, lane l) 32B = {e' ks0, e' ks1} fp16, e' = 1024*e

__device__ inline ushort f2h(float f) { return __half_as_ushort(__float2half_rn(f)); }

// XOR swizzle within a 128B row (T2/G4): kills 16-lane same-column bank conflicts
__device__ inline uint swz(uint row, uint b) { return row * 128u + (b ^ ((row & 7u) << 4)); }

__global__ void vq_prep(const float* __restrict__ emb, float* __restrict__ nh,
                        int* __restrict__ counts8, ushort* __restrict__ blob) {
    int g = blockIdx.x * 256 + threadIdx.x;     // 0..4095 == (c*4+q)*64+l
    int l = g & 63;
    int l15 = l & 15, lhi = l >> 4;
    int c = g >> 8, q = (g >> 6) & 3;
    int code = c * 64 + q * 16 + l15;
    int k0 = lhi * 8;
    const float* er = emb + (size_t)code * DIM;

    ushort tmp[16];
    #pragma unroll
    for (int j = 0; j < 8; ++j) {
        tmp[j]     = f2h(er[k0 + j]      * 1024.0f);
        tmp[8 + j] = f2h(er[32 + k0 + j] * 1024.0f);
    }
    ushort* dst = blob + (size_t)g * 16;        // 32 bytes
    *(short8*)(dst)     = *(const short8*)(tmp);
    *(short8*)(dst + 8) = *(const short8*)(tmp + 8);

    counts8[2 * g]     = 0;                     // zero all 8192 shard entries
    counts8[2 * g + 1] = 0;

    if (g < NCODES) {
        const float4* e4 = (const float4*)(emb + (size_t)g * DIM);
        float s = 0.f;
        #pragma unroll
        for (int d = 0; d < 16; ++d) {
            float4 v = e4[d];
            s += v.x * v.x + v.y * v.y + v.z * v.z + v.w * v.w;
        }
        nh[g] = 64.0f - 512.0f * s;
    }
}

__global__ __launch_bounds__(TPB, 3) void vq_main(
        const float* __restrict__ x, const float* __restrict__ emb,
        const ushort* __restrict__ blob, const float* __restrict__ nh,
        float* __restrict__ out, int* __restrict__ counts8, float* __restrict__ ssePart) {

    __shared__ __align__(16) ushort xh[MB * DIM];    // 16KB, swizzled fp16 of x
    __shared__ uint  part1[MB][4];
    __shared__ int   rowIdx[MB];
    __shared__ float wred[8];

    const int tid = threadIdx.x;
    const int lane = tid & 63;
    const int w = tid >> 6;             // wave 0..7
    const int wq = w & 3;               // code-quarter: codes [wq*16, wq*16+16) per chunk
    const int rowHalf = (w >> 2) * 64;  // rows [rowHalf, rowHalf+64)
    const int l15 = lane & 15, lhi = lane >> 4;
    const int rowBase = blockIdx.x * MB;

    // ---- stage x as fp16 (swizzled), once per block ----
    #pragma unroll
    for (int i = 0; i < 4; ++i) {
        int f = tid + TPB * i; int r = f >> 4, d4 = f & 15;
        float4 v = ((const float4*)x)[(size_t)(rowBase + r) * 16 + d4];
        ushort4 h = make_ushort4(f2h(v.x), f2h(v.y), f2h(v.z), f2h(v.w));
        *(ushort4*)((char*)xh + swz((uint)r, (uint)d4 * 8u)) = h;
    }
    __syncthreads();

    // ---- A fragments (fp16 x) register-resident ----
    short8 afr[4][2];
    #pragma unroll
    for (int rm = 0; rm < 4; ++rm)
        #pragma unroll
        for (int ks = 0; ks < 2; ++ks)
            afr[rm][ks] = *(const short8*)((char*)xh + swz((uint)(rowHalf + rm * 16 + l15),
                                                           (uint)(ks * 64 + lhi * 16)));

    uint keys[16];
    #pragma unroll
    for (int s = 0; s < 16; ++s) keys[s] = 0u;

    const int codeBase = wq * 16 + l15;            // code offset within a chunk
    const ushort* bp = blob + ((size_t)wq * 64 + lane) * 16;  // +4096 ushorts per chunk

    // one chunk: scores + single-u32 packed-key update; C-init fused into first MFMA
    // key = (bits(score) & ~1023) | (1023 - global_code); u32 max == min dist, min code on tie
    auto body = [&](short8 f0, short8 f1, float nhv, uint invc) {
        floatx4 nhq = (floatx4){nhv, nhv, nhv, nhv};
        floatx4 acc[4];
        #pragma unroll
        for (int rm = 0; rm < 4; ++rm) {
            acc[rm] = __builtin_amdgcn_mfma_f32_16x16x32_f16(afr[rm][0], f0, nhq, 0, 0, 0);
            acc[rm] = __builtin_amdgcn_mfma_f32_16x16x32_f16(afr[rm][1], f1, acc[rm], 0, 0, 0);
        }
        #pragma unroll
        for (int rm = 0; rm < 4; ++rm)
            #pragma unroll
            for (int j = 0; j < 4; ++j) {
                uint kb = (__float_as_uint(acc[rm][j]) & 0xFFFFFC00u) | invc;
                int s = rm * 4 + j;
                keys[s] = keys[s] > kb ? keys[s] : kb;
            }
    };

    // ---- ping-pong pair pipeline: zero register moves, rolled (unroll OFF), tails peeled ----
    short8 a0 = *(const short8*)(bp);
    short8 a1 = *(const short8*)(bp + 8);
    short8 b0 = *(const short8*)(bp + 4096);
    short8 b1 = *(const short8*)(bp + 4096 + 8);
    float  nhA = nh[codeBase];
    float  nhB = nh[64 + codeBase];
    uint   invc = 1023u - (uint)codeBase;

    #pragma unroll 1
    for (int c = 0; c < NCHUNK - 2; c += 2) {
        body(a0, a1, nhA, invc);                 // chunk c
        const ushort* fa = bp + (size_t)(c + 2) * 4096;
        a0 = *(const short8*)(fa);               // reload A <- chunk c+2
        a1 = *(const short8*)(fa + 8);
        nhA = nh[(c + 2) * 64 + codeBase];

        body(b0, b1, nhB, invc - 64u);           // chunk c+1
        const ushort* fb = bp + (size_t)(c + 3) * 4096;
        b0 = *(const short8*)(fb);               // reload B <- chunk c+3
        b1 = *(const short8*)(fb + 8);
        nhB = nh[(c + 3) * 64 + codeBase];

        invc -= 128u;
    }
    body(a0, a1, nhA, invc);                     // chunk 14
    body(b0, b1, nhB, invc - 64u);               // chunk 15

    // ---- hoist epilogue x reloads: independent of merge, latency hides under barriers ----
    float4 xv[4];
    #pragma unroll
    for (int i = 0; i < 4; ++i) {
        int f = tid + TPB * i;
        xv[i] = ((const float4*)x)[(size_t)(rowBase + (f >> 4)) * 16 + (f & 15)];
    }

    // ---- cross-lane merge within each 16-lane code group: plain u32 max ----
    #pragma unroll
    for (int s = 0; s < 16; ++s) {
        uint k = keys[s];
        #pragma unroll
        for (int m = 1; m < 16; m <<= 1) {
            uint ok = __shfl_xor(k, m);
            k = ok > k ? ok : k;
        }
        if (l15 == 0)
            part1[rowHalf + (s >> 2) * 16 + lhi * 4 + (s & 3)][wq] = k;
    }
    __syncthreads();

    // ---- per-row merge of 4 wave partials (u32 max; code embedded) ----
    if (tid < MB) {
        uint p = part1[tid][0];
        #pragma unroll
        for (int g = 1; g < 4; ++g) {
            uint q = part1[tid][g];
            p = q > p ? q : p;
        }
        int code = 1023 - (int)(p & 1023u);
        rowIdx[tid] = code;
        atomicAdd(&counts8[(blockIdx.x & 7) * NCODES + code], 1);
    }
    __syncthreads();

    // ---- epilogue: gather, straight-through out, SSE partial ----
    float myss = 0.f;
    #pragma unroll
    for (int i = 0; i < 4; ++i) {
        int f = tid + TPB * i; int r = f >> 4, d4 = f & 15;
        int idx = rowIdx[r];
        float4 q = ((const float4*)emb)[(size_t)idx * 16 + d4];
        float4 o;
        o.x = xv[i].x + (q.x - xv[i].x);
        o.y = xv[i].y + (q.y - xv[i].y);
        o.z = xv[i].z + (q.z - xv[i].z);
        o.w = xv[i].w + (q.w - xv[i].w);
        ((float4*)out)[(size_t)(rowBase + r) * 16 + d4] = o;
        float gx = o.x - xv[i].x, gy = o.y - xv[i].y, gz = o.z - xv[i].z, gw = o.w - xv[i].w;
        myss += gx * gx + gy * gy + gz * gz + gw * gw;
    }
    #pragma unroll
    for (int m = 32; m >= 1; m >>= 1) myss += __shfl_down(myss, m);
    if (lane == 0) wred[w] = myss;
    __syncthreads();
    if (tid == 0) {
        float s = 0.f;
        #pragma unroll
        for (int i = 0; i < 8; ++i) s += wred[i];
        ssePart[blockIdx.x] = s;
    }
}

__global__ void vq_final(const int* __restrict__ counts8, const float* __restrict__ ssePart,
                         float* __restrict__ out) {
    __shared__ float pe[16], ps[16];
    int k = threadIdx.x;   // 1024 threads
    int cnt = 0;
    #pragma unroll
    for (int s = 0; s < 8; ++s) cnt += counts8[s * NCODES + k];
    float p = (float)cnt * (1.0f / (float)N_ROWS);
    float ent = p * logf(p + 1e-10f);
    float sp = ssePart[k];
    #pragma unroll
    for (int m = 32; m >= 1; m >>= 1) {
        ent += __shfl_down(ent, m);
        sp  += __shfl_down(sp, m);
    }
    if ((k & 63) == 0) { pe[k >> 6] = ent; ps[k >> 6] = sp; }
    __syncthreads();
    if (k == 0) {
        float es = 0.f, ss = 0.f;
        #pragma unroll
        for (int w = 0; w < 16; ++w) { es += pe[w]; ss += ps[w]; }
        out[(size_t)N_ROWS * DIM]     = 1.25f * (ss / (float)(N_ROWS * DIM));
        out[(size_t)N_ROWS * DIM + 1] = expf(-es);
    }
}

extern "C" void kernel_launch(void* const* d_in, const int* in_sizes, int n_in,
                              void* d_out, int out_size, void* d_ws, size_t ws_size,
                              hipStream_t stream) {
    const float* x   = (const float*)d_in[0];
    const float* emb = (const float*)d_in[1];
    float*  out     = (float*)d_out;
    float*  nh      = (float*)d_ws;
    int*    counts8 = (int*)((char*)d_ws + 4096);
    float*  ssePrt  = (float*)((char*)d_ws + 36864);
    ushort* blob    = (ushort*)((char*)d_ws + 40960);

    vq_prep<<<16, 256, 0, stream>>>(emb, nh, counts8, blob);
    vq_main<<<NBLK, TPB, 0, stream>>>(x, emb, blob, nh, out, counts8, ssePrt);
    vq_final<<<1, 1024, 0, stream>>>(counts8, ssePrt, out);
}

// Round 20
// 44.066 us; speedup vs baseline: 1.1678x; 1.1678x over previous
//
#include <hip/hip_runtime.h>
#include <hip/hip_fp16.h>
#include <float.h>

#define N_ROWS   131072
#define DIM      64
#define NCODES   1024
#define MB       128     // rows per block
#define TPB      512     // 8 waves
#define NCHUNK   16      // 64 codes per chunk
#define NBLK     (N_ROWS / MB)   // 1024

typedef __attribute__((ext_vector_type(8))) short short8;
typedef __attribute__((ext_vector_type(4))) float floatx4;

// ws layout (bytes):
// [0,     4096)   nh      f32[1024]    64 - 512*||e_k||^2
// [4096,  36864)  counts8 i32[8][1024] sharded histogram (blockIdx&7)
// [36864, 40960)  ssePart f32[1024]
// [40960, 172032) blob: per (chunk c, quarter q, lane l) 32B = {e' ks0, e' ks1} fp16, e' = 1024*e

__device__ inline ushort f2h(float f) { return __half_as_ushort(__float2half_rn(f)); }

// XOR swizzle within a 128B row (T2/G4): kills 16-lane same-column bank conflicts
__device__ inline uint swz(uint row, uint b) { return row * 128u + (b ^ ((row & 7u) << 4)); }

__global__ void vq_prep(const float* __restrict__ emb, float* __restrict__ nh,
                        int* __restrict__ counts8, ushort* __restrict__ blob) {
    int g = blockIdx.x * 256 + threadIdx.x;     // 0..4095 == (c*4+q)*64+l
    int l = g & 63;
    int l15 = l & 15, lhi = l >> 4;
    int c = g >> 8, q = (g >> 6) & 3;
    int code = c * 64 + q * 16 + l15;
    int k0 = lhi * 8;
    const float* er = emb + (size_t)code * DIM;

    ushort tmp[16];
    #pragma unroll
    for (int j = 0; j < 8; ++j) {
        tmp[j]     = f2h(er[k0 + j]      * 1024.0f);
        tmp[8 + j] = f2h(er[32 + k0 + j] * 1024.0f);
    }
    ushort* dst = blob + (size_t)g * 16;        // 32 bytes
    *(short8*)(dst)     = *(const short8*)(tmp);
    *(short8*)(dst + 8) = *(const short8*)(tmp + 8);

    counts8[2 * g]     = 0;                     // zero all 8192 shard entries
    counts8[2 * g + 1] = 0;

    if (g < NCODES) {
        const float4* e4 = (const float4*)(emb + (size_t)g * DIM);
        float s = 0.f;
        #pragma unroll
        for (int d = 0; d < 16; ++d) {
            float4 v = e4[d];
            s += v.x * v.x + v.y * v.y + v.z * v.z + v.w * v.w;
        }
        nh[g] = 64.0f - 512.0f * s;
    }
}

__global__ __launch_bounds__(TPB, 3) void vq_main(
        const float* __restrict__ x, const float* __restrict__ emb,
        const ushort* __restrict__ blob, const float* __restrict__ nh,
        float* __restrict__ out, int* __restrict__ counts8, float* __restrict__ ssePart) {

    __shared__ __align__(16) ushort xh[MB * DIM];    // 16KB, swizzled fp16 of x
    __shared__ uint  part1[MB][4];
    __shared__ int   rowIdx[MB];
    __shared__ float wred[8];

    const int tid = threadIdx.x;
    const int lane = tid & 63;
    const int w = tid >> 6;             // wave 0..7
    const int wq = w & 3;               // code-quarter: codes [wq*16, wq*16+16) per chunk
    const int rowHalf = (w >> 2) * 64;  // rows [rowHalf, rowHalf+64)
    const int l15 = lane & 15, lhi = lane >> 4;
    const int rowBase = blockIdx.x * MB;

    // ---- stage x as fp16 (swizzled), once per block ----
    #pragma unroll
    for (int i = 0; i < 4; ++i) {
        int f = tid + TPB * i; int r = f >> 4, d4 = f & 15;
        float4 v = ((const float4*)x)[(size_t)(rowBase + r) * 16 + d4];
        ushort4 h = make_ushort4(f2h(v.x), f2h(v.y), f2h(v.z), f2h(v.w));
        *(ushort4*)((char*)xh + swz((uint)r, (uint)d4 * 8u)) = h;
    }
    __syncthreads();

    // ---- A fragments (fp16 x) register-resident ----
    short8 afr[4][2];
    #pragma unroll
    for (int rm = 0; rm < 4; ++rm)
        #pragma unroll
        for (int ks = 0; ks < 2; ++ks)
            afr[rm][ks] = *(const short8*)((char*)xh + swz((uint)(rowHalf + rm * 16 + l15),
                                                           (uint)(ks * 64 + lhi * 16)));

    uint keys[16];
    #pragma unroll
    for (int s = 0; s < 16; ++s) keys[s] = 0u;

    const int codeBase = wq * 16 + l15;            // code offset within a chunk
    const ushort* bp = blob + ((size_t)wq * 64 + lane) * 16;  // +4096 ushorts per chunk

    // one chunk: scores + single-u32 packed-key update; C-init fused into first MFMA
    // key = (bits(score) & ~1023) | (1023 - global_code); u32 max == min dist, min code on tie
    auto body = [&](short8 f0, short8 f1, float nhv, uint invc) {
        floatx4 nhq = (floatx4){nhv, nhv, nhv, nhv};
        floatx4 acc[4];
        #pragma unroll
        for (int rm = 0; rm < 4; ++rm) {
            acc[rm] = __builtin_amdgcn_mfma_f32_16x16x32_f16(afr[rm][0], f0, nhq, 0, 0, 0);
            acc[rm] = __builtin_amdgcn_mfma_f32_16x16x32_f16(afr[rm][1], f1, acc[rm], 0, 0, 0);
        }
        #pragma unroll
        for (int rm = 0; rm < 4; ++rm)
            #pragma unroll
            for (int j = 0; j < 4; ++j) {
                uint kb = (__float_as_uint(acc[rm][j]) & 0xFFFFFC00u) | invc;
                int s = rm * 4 + j;
                keys[s] = keys[s] > kb ? keys[s] : kb;
            }
    };

    // ---- 2-deep register pipeline: cur / nxt / fut, rolled (unroll OFF), 2 peeled tails ----
    short8 cur0 = *(const short8*)(bp);
    short8 cur1 = *(const short8*)(bp + 8);
    float  nhc  = nh[codeBase];
    short8 nxt0 = *(const short8*)(bp + 4096);
    short8 nxt1 = *(const short8*)(bp + 4096 + 8);
    float  nhn  = nh[64 + codeBase];
    uint   invc = 1023u - (uint)codeBase;

    #pragma unroll 1
    for (int c = 0; c < NCHUNK - 2; ++c) {
        const ushort* fp = bp + (size_t)(c + 2) * 4096;
        short8 fut0 = *(const short8*)(fp);
        short8 fut1 = *(const short8*)(fp + 8);
        float  nhf  = nh[(c + 2) * 64 + codeBase];

        body(cur0, cur1, nhc, invc);

        cur0 = nxt0; cur1 = nxt1; nhc = nhn;
        nxt0 = fut0; nxt1 = fut1; nhn = nhf;
        invc -= 64u;
    }
    body(cur0, cur1, nhc, invc);                 // chunk 14
    cur0 = nxt0; cur1 = nxt1; nhc = nhn; invc -= 64u;
    body(cur0, cur1, nhc, invc);                 // chunk 15

    // ---- hoist epilogue x reloads: independent of merge, latency hides under barriers ----
    float4 xv[4];
    #pragma unroll
    for (int i = 0; i < 4; ++i) {
        int f = tid + TPB * i;
        xv[i] = ((const float4*)x)[(size_t)(rowBase + (f >> 4)) * 16 + (f & 15)];
    }

    // ---- cross-lane merge within each 16-lane code group: plain u32 max ----
    #pragma unroll
    for (int s = 0; s < 16; ++s) {
        uint k = keys[s];
        #pragma unroll
        for (int m = 1; m < 16; m <<= 1) {
            uint ok = __shfl_xor(k, m);
            k = ok > k ? ok : k;
        }
        if (l15 == 0)
            part1[rowHalf + (s >> 2) * 16 + lhi * 4 + (s & 3)][wq] = k;
    }
    __syncthreads();

    // ---- per-row merge of 4 wave partials (u32 max; code embedded) ----
    if (tid < MB) {
        uint p = part1[tid][0];
        #pragma unroll
        for (int g = 1; g < 4; ++g) {
            uint q = part1[tid][g];
            p = q > p ? q : p;
        }
        int code = 1023 - (int)(p & 1023u);
        rowIdx[tid] = code;
        atomicAdd(&counts8[(blockIdx.x & 7) * NCODES + code], 1);
    }
    __syncthreads();

    // ---- epilogue: gather, straight-through out, SSE partial ----
    float myss = 0.f;
    #pragma unroll
    for (int i = 0; i < 4; ++i) {
        int f = tid + TPB * i; int r = f >> 4, d4 = f & 15;
        int idx = rowIdx[r];
        float4 q = ((const float4*)emb)[(size_t)idx * 16 + d4];
        float4 o;
        o.x = xv[i].x + (q.x - xv[i].x);
        o.y = xv[i].y + (q.y - xv[i].y);
        o.z = xv[i].z + (q.z - xv[i].z);
        o.w = xv[i].w + (q.w - xv[i].w);
        ((float4*)out)[(size_t)(rowBase + r) * 16 + d4] = o;
        float gx = o.x - xv[i].x, gy = o.y - xv[i].y, gz = o.z - xv[i].z, gw = o.w - xv[i].w;
        myss += gx * gx + gy * gy + gz * gz + gw * gw;
    }
    #pragma unroll
    for (int m = 32; m >= 1; m >>= 1) myss += __shfl_down(myss, m);
    if (lane == 0) wred[w] = myss;
    __syncthreads();
    if (tid == 0) {
        float s = 0.f;
        #pragma unroll
        for (int i = 0; i < 8; ++i) s += wred[i];
        ssePart[blockIdx.x] = s;
    }
}

__global__ void vq_final(const int* __restrict__ counts8, const float* __restrict__ ssePart,
                         float* __restrict__ out) {
    __shared__ float pe[16], ps[16];
    int k = threadIdx.x;   // 1024 threads
    int cnt = 0;
    #pragma unroll
    for (int s = 0; s < 8; ++s) cnt += counts8[s * NCODES + k];
    float p = (float)cnt * (1.0f / (float)N_ROWS);
    float ent = p * logf(p + 1e-10f);
    float sp = ssePart[k];
    #pragma unroll
    for (int m = 32; m >= 1; m >>= 1) {
        ent += __shfl_down(ent, m);
        sp  += __shfl_down(sp, m);
    }
    if ((k & 63) == 0) { pe[k >> 6] = ent; ps[k >> 6] = sp; }
    __syncthreads();
    if (k == 0) {
        float es = 0.f, ss = 0.f;
        #pragma unroll
        for (int w = 0; w < 16; ++w) { es += pe[w]; ss += ps[w]; }
        out[(size_t)N_ROWS * DIM]     = 1.25f * (ss / (float)(N_ROWS * DIM));
        out[(size_t)N_ROWS * DIM + 1] = expf(-es);
    }
}

extern "C" void kernel_launch(void* const* d_in, const int* in_sizes, int n_in,
                              void* d_out, int out_size, void* d_ws, size_t ws_size,
                              hipStream_t stream) {
    const float* x   = (const float*)d_in[0];
    const float* emb = (const float*)d_in[1];
    float*  out     = (float*)d_out;
    float*  nh      = (float*)d_ws;
    int*    counts8 = (int*)((char*)d_ws + 4096);
    float*  ssePrt  = (float*)((char*)d_ws + 36864);
    ushort* blob    = (ushort*)((char*)d_ws + 40960);

    vq_prep<<<16, 256, 0, stream>>>(emb, nh, counts8, blob);
    vq_main<<<NBLK, TPB, 0, stream>>>(x, emb, blob, nh, out, counts8, ssePrt);
    vq_final<<<1, 1024, 0, stream>>>(counts8, ssePrt, out);
}